// Round 1
// baseline (434.014 us; speedup 1.0000x reference)
//
#include <hip/hip_runtime.h>
#include <hip/hip_bf16.h>

#define TOKENS 16384
#define DIM 1024
#define HID 4096

typedef __attribute__((ext_vector_type(8))) short short8;
typedef __attribute__((ext_vector_type(4))) float f32x4;

__device__ __forceinline__ unsigned short f2bf(float f) {
  union { float f; unsigned int u; } v; v.f = f;
  unsigned int r = v.u + 0x7fffu + ((v.u >> 16) & 1u);
  return (unsigned short)(r >> 16);
}

__device__ __forceinline__ void async16(const void* g, void* lds) {
  __builtin_amdgcn_global_load_lds((const __attribute__((address_space(1))) void*)g,
                                   (__attribute__((address_space(3))) void*)lds, 16, 0, 0);
}

// ---------------------------------------------------------------------------
// Router: fp64-accurate logits, mask compaction, output=x prefill, x -> bf16.
// One wave per token, 4 waves/block.
// ---------------------------------------------------------------------------
__global__ __launch_bounds__(256) void router_kernel(
    const float* __restrict__ x, const float* __restrict__ Wr, const float* __restrict__ br,
    float* __restrict__ out, unsigned short* __restrict__ xb,
    int* __restrict__ idx, int* __restrict__ counter)
{
  int wid = threadIdx.x >> 6, lane = threadIdx.x & 63;
  int token = blockIdx.x * 4 + wid;
  const float4* xr  = (const float4*)(x + (size_t)token * DIM);
  const float4* wr4 = (const float4*)Wr;
  float4* outr = (float4*)(out + (size_t)token * DIM);
  ushort4* xbr = (ushort4*)(xb + (size_t)token * DIM);
  double s = 0.0;
#pragma unroll
  for (int j = 0; j < 4; ++j) {
    float4 v = xr[lane + 64 * j];
    float4 w = wr4[lane + 64 * j];
    s += (double)v.x * w.x + (double)v.y * w.y + (double)v.z * w.z + (double)v.w * w.w;
    outr[lane + 64 * j] = v;
    ushort4 u;
    u.x = f2bf(v.x); u.y = f2bf(v.y); u.z = f2bf(v.z); u.w = f2bf(v.w);
    xbr[lane + 64 * j] = u;
  }
#pragma unroll
  for (int off = 32; off > 0; off >>= 1) s += __shfl_down(s, off);
  if (lane == 0) {
    float logit = (float)s + br[0];
    if (logit > 0.0f) {              // sigmoid(logit) > 0.5
      int p = atomicAdd(counter, 1);
      idx[p] = token;
    }
  }
}

// ---------------------------------------------------------------------------
// Transpose + fp32->bf16 cast: W [R][C] fp32 -> Wt [C][R] bf16 (for B^T GEMM).
// ---------------------------------------------------------------------------
__global__ __launch_bounds__(256) void transpose_cast_kernel(
    const float* __restrict__ W, unsigned short* __restrict__ Wt, int R, int C)
{
  __shared__ float tile[32][33];
  int tx = threadIdx.x & 31, ty = threadIdx.x >> 5;  // 32 x 8
  int c0 = blockIdx.x * 32, r0 = blockIdx.y * 32;
#pragma unroll
  for (int i = 0; i < 32; i += 8)
    tile[ty + i][tx] = W[(size_t)(r0 + ty + i) * C + (c0 + tx)];
  __syncthreads();
#pragma unroll
  for (int i = 0; i < 32; i += 8)
    Wt[(size_t)(c0 + ty + i) * R + (r0 + tx)] = f2bf(tile[tx][ty + i]);
}

__global__ void frac_kernel(const int* __restrict__ counter, float* __restrict__ fr)
{
  fr[0] = (float)(*counter) * (1.0f / (float)TOKENS);
}

// ---------------------------------------------------------------------------
// bf16 GEMM, m97 structure: 128x128 tile, 4 waves (each 64x64 = 4x4 frags of
// 16x16x32), BK=32, global_load_lds width-16 staging, B^T operand layout.
// FIRST:  A = xb gathered via idx, out = h (bf16, relu(acc+b1)), compact rows.
// !FIRST: A = h compact, out = scatter fp32 acc+b2 to d_out at idx[row].
// ---------------------------------------------------------------------------
template<int N, int K, bool FIRST>
__global__ __launch_bounds__(256) void gemm_kernel(
    const unsigned short* __restrict__ A, const unsigned short* __restrict__ Bt,
    const float* __restrict__ bias, const int* __restrict__ idxp,
    const int* __restrict__ counter,
    unsigned short* __restrict__ Hout, float* __restrict__ Cout)
{
  int cnt = *counter;
  int row0 = blockIdx.y * 128;
  if (row0 >= cnt) return;
  int col0 = blockIdx.x * 128;

  __shared__ unsigned short As[128 * 32];
  __shared__ unsigned short Bs[128 * 32];
  __shared__ int rowIdx[128];

  int tid = threadIdx.x, wid = tid >> 6, lane = tid & 63;
  if (tid < 128) rowIdx[tid] = idxp[row0 + tid];
  __syncthreads();

  // staging addresses: each thread owns two 16B chunks per K-step
  int sRow0 = wid * 16 + (lane >> 2);
  int sRow1 = 64 + sRow0;
  int chunk = (lane & 3) * 8;
  int ar0 = FIRST ? rowIdx[sRow0] : (row0 + sRow0);
  int ar1 = FIRST ? rowIdx[sRow1] : (row0 + sRow1);
  const unsigned short* gA0 = A + (size_t)ar0 * K + chunk;
  const unsigned short* gA1 = A + (size_t)ar1 * K + chunk;
  const unsigned short* gB0 = Bt + (size_t)(col0 + sRow0) * K + chunk;
  const unsigned short* gB1 = Bt + (size_t)(col0 + sRow1) * K + chunk;
  unsigned short* lA0 = As + (size_t)(wid * 16) * 32;        // wave-uniform bases
  unsigned short* lA1 = As + (size_t)(64 + wid * 16) * 32;
  unsigned short* lB0 = Bs + (size_t)(wid * 16) * 32;
  unsigned short* lB1 = Bs + (size_t)(64 + wid * 16) * 32;

  f32x4 acc[4][4];
#pragma unroll
  for (int i = 0; i < 4; ++i)
#pragma unroll
    for (int j = 0; j < 4; ++j) acc[i][j] = (f32x4){0.f, 0.f, 0.f, 0.f};

  int wr = (wid >> 1) * 64, wc = (wid & 1) * 64;
  int frow = lane & 15, khalf = lane >> 4;

  for (int k0 = 0; k0 < K; k0 += 32) {
    async16(gA0 + k0, lA0);
    async16(gA1 + k0, lA1);
    async16(gB0 + k0, lB0);
    async16(gB1 + k0, lB1);
    __syncthreads();   // drains vmcnt(0) before barrier -> LDS tile visible
    short8 af[4], bfr[4];
#pragma unroll
    for (int mi = 0; mi < 4; ++mi)
      af[mi] = *(const short8*)&As[(size_t)(wr + mi * 16 + frow) * 32 + khalf * 8];
#pragma unroll
    for (int ni = 0; ni < 4; ++ni)
      bfr[ni] = *(const short8*)&Bs[(size_t)(wc + ni * 16 + frow) * 32 + khalf * 8];
#pragma unroll
    for (int mi = 0; mi < 4; ++mi)
#pragma unroll
      for (int ni = 0; ni < 4; ++ni)
        acc[mi][ni] = __builtin_amdgcn_mfma_f32_16x16x32_bf16(af[mi], bfr[ni], acc[mi][ni], 0, 0, 0);
    __syncthreads();   // protect LDS before next stage overwrites
  }

  // epilogue: C/D layout col = lane&15, row = (lane>>4)*4 + reg   [m89/m91]
  int cl = lane & 15, rq = lane >> 4;
#pragma unroll
  for (int mi = 0; mi < 4; ++mi) {
#pragma unroll
    for (int ni = 0; ni < 4; ++ni) {
      int col = col0 + wc + ni * 16 + cl;
      float bv = bias[col];
#pragma unroll
      for (int r = 0; r < 4; ++r) {
        int rloc = wr + mi * 16 + rq * 4 + r;
        int grow = row0 + rloc;
        float val = acc[mi][ni][r] + bv;
        if (FIRST) {
          val = val > 0.f ? val : 0.f;
          Hout[(size_t)grow * N + col] = f2bf(val);
        } else if (grow < cnt) {
          int tok = rowIdx[rloc];
          Cout[(size_t)tok * DIM + col] = val;
        }
      }
    }
  }
}

// ---------------------------------------------------------------------------
extern "C" void kernel_launch(void* const* d_in, const int* in_sizes, int n_in,
                              void* d_out, int out_size, void* d_ws, size_t ws_size,
                              hipStream_t stream)
{
  const float* x  = (const float*)d_in[0];
  const float* Wr = (const float*)d_in[1];
  const float* br = (const float*)d_in[2];
  const float* W1 = (const float*)d_in[3];
  const float* b1 = (const float*)d_in[4];
  const float* W2 = (const float*)d_in[5];
  const float* b2 = (const float*)d_in[6];
  float* out = (float*)d_out;

  char* ws = (char*)d_ws;
  int* counter        = (int*)ws;                          // 4 B (zeroed)
  int* idx            = (int*)(ws + 256);                  // 64 KB (zeroed)
  unsigned short* xb  = (unsigned short*)(ws + (1ull  << 20));  // 32 MB bf16 x
  unsigned short* W1T = (unsigned short*)(ws + (34ull << 20));  // 8 MB  bf16 W1^T [4096][1024]
  unsigned short* W2T = (unsigned short*)(ws + (44ull << 20));  // 8 MB  bf16 W2^T [1024][4096]
  unsigned short* h   = (unsigned short*)(ws + (54ull << 20));  // 128 MB bf16 h (worst case)

  hipMemsetAsync(ws, 0, 256 + TOKENS * 4, stream);  // counter + idx

  router_kernel<<<TOKENS / 4, 256, 0, stream>>>(x, Wr, br, out, xb, idx, counter);
  transpose_cast_kernel<<<dim3(HID / 32, DIM / 32), 256, 0, stream>>>(W1, W1T, DIM, HID);
  transpose_cast_kernel<<<dim3(DIM / 32, HID / 32), 256, 0, stream>>>(W2, W2T, HID, DIM);
  frac_kernel<<<1, 1, 0, stream>>>(counter, out + (size_t)TOKENS * DIM);

  gemm_kernel<HID, DIM, true><<<dim3(HID / 128, TOKENS / 128), 256, 0, stream>>>(
      xb, W1T, b1, idx, counter, h, nullptr);
  gemm_kernel<DIM, HID, false><<<dim3(DIM / 128, TOKENS / 128), 256, 0, stream>>>(
      h, W2T, b2, idx, counter, nullptr, out);
}

// Round 2
// 383.660 us; speedup vs baseline: 1.1312x; 1.1312x over previous
//
#include <hip/hip_runtime.h>
#include <hip/hip_bf16.h>

#define TOKENS 16384
#define DIM 1024
#define HID 4096

typedef __attribute__((ext_vector_type(8))) short short8;
typedef __attribute__((ext_vector_type(4))) float f32x4;

__device__ __forceinline__ unsigned short f2bf(float f) {
  union { float f; unsigned int u; } v; v.f = f;
  unsigned int r = v.u + 0x7fffu + ((v.u >> 16) & 1u);
  return (unsigned short)(r >> 16);
}

__device__ __forceinline__ void async16(const void* g, void* lds) {
  __builtin_amdgcn_global_load_lds((const __attribute__((address_space(1))) void*)g,
                                   (__attribute__((address_space(3))) void*)lds, 16, 0, 0);
}

// ---------------------------------------------------------------------------
// Router v2: 16 tokens/block (4 waves x 4 tokens each), fp64 logits.
// Selected tokens  -> xb (bf16) only.
// Unselected       -> out (fp32 passthrough) only.
// ONE atomicAdd per block (vs per-token): kills same-address serialization.
// ---------------------------------------------------------------------------
__global__ __launch_bounds__(256) void router_kernel(
    const float* __restrict__ x, const float* __restrict__ Wr, const float* __restrict__ br,
    float* __restrict__ out, unsigned short* __restrict__ xb,
    int* __restrict__ idx, int* __restrict__ counter)
{
  __shared__ unsigned char selLds[16];
  int wid = threadIdx.x >> 6, lane = threadIdx.x & 63;
  const float4* wr4 = (const float4*)Wr;
  float4 w[4];
#pragma unroll
  for (int j = 0; j < 4; ++j) w[j] = wr4[lane + 64 * j];
  float b0 = br[0];

#pragma unroll
  for (int t = 0; t < 4; ++t) {
    int token = blockIdx.x * 16 + wid * 4 + t;
    const float4* xr = (const float4*)(x + (size_t)token * DIM);
    float4 v[4];
#pragma unroll
    for (int j = 0; j < 4; ++j) v[j] = xr[lane + 64 * j];
    double s = 0.0;
#pragma unroll
    for (int j = 0; j < 4; ++j)
      s += (double)v[j].x * w[j].x + (double)v[j].y * w[j].y +
           (double)v[j].z * w[j].z + (double)v[j].w * w[j].w;
#pragma unroll
    for (int off = 32; off > 0; off >>= 1) s += __shfl_xor(s, off);
    bool sel = ((float)s + b0) > 0.0f;          // sigmoid(logit) > 0.5
    if (sel) {
      ushort4* xbr = (ushort4*)(xb + (size_t)token * DIM);
#pragma unroll
      for (int j = 0; j < 4; ++j) {
        ushort4 u;
        u.x = f2bf(v[j].x); u.y = f2bf(v[j].y); u.z = f2bf(v[j].z); u.w = f2bf(v[j].w);
        xbr[lane + 64 * j] = u;
      }
    } else {
      float4* outr = (float4*)(out + (size_t)token * DIM);
#pragma unroll
      for (int j = 0; j < 4; ++j) outr[lane + 64 * j] = v[j];
    }
    if (lane == 0) selLds[wid * 4 + t] = sel ? 1 : 0;
  }
  __syncthreads();
  if (threadIdx.x == 0) {
    int cnt = 0;
#pragma unroll
    for (int i = 0; i < 16; ++i) cnt += selLds[i];
    int p = atomicAdd(counter, cnt);
#pragma unroll
    for (int i = 0; i < 16; ++i)
      if (selLds[i]) idx[p++] = blockIdx.x * 16 + i;
  }
}

// ---------------------------------------------------------------------------
// Transpose + fp32->bf16 cast: W [R][C] fp32 -> Wt [C][R] bf16 (for B^T GEMM).
// ---------------------------------------------------------------------------
__global__ __launch_bounds__(256) void transpose_cast_kernel(
    const float* __restrict__ W, unsigned short* __restrict__ Wt, int R, int C)
{
  __shared__ float tile[32][33];
  int tx = threadIdx.x & 31, ty = threadIdx.x >> 5;  // 32 x 8
  int c0 = blockIdx.x * 32, r0 = blockIdx.y * 32;
#pragma unroll
  for (int i = 0; i < 32; i += 8)
    tile[ty + i][tx] = W[(size_t)(r0 + ty + i) * C + (c0 + tx)];
  __syncthreads();
#pragma unroll
  for (int i = 0; i < 32; i += 8)
    Wt[(size_t)(c0 + ty + i) * R + (r0 + tx)] = f2bf(tile[tx][ty + i]);
}

__global__ void frac_kernel(const int* __restrict__ counter, float* __restrict__ fr)
{
  fr[0] = (float)(*counter) * (1.0f / (float)TOKENS);
}

// ---------------------------------------------------------------------------
// bf16 GEMM, m97 structure: 128x128 tile, 4 waves (each 64x64 = 4x4 frags of
// 16x16x32), BK=32, global_load_lds width-16 staging, B^T operand layout.
// 1D grid, bijective XCD swizzle (m204) + COL-MAJOR decode: each XCD owns a
// contiguous run of row-tiles of the SAME column panel -> B panel L2-resident,
// A stream shared across XCDs via L3 (all XCDs walk rows in near-lockstep).
// FIRST:  A = xb gathered via idx, out = h (bf16, relu(acc+b1)), compact rows.
// !FIRST: A = h compact, out = scatter fp32 acc+b2 to d_out at idx[row].
// ---------------------------------------------------------------------------
template<int N, int K, bool FIRST>
__global__ __launch_bounds__(256) void gemm_kernel(
    const unsigned short* __restrict__ A, const unsigned short* __restrict__ Bt,
    const float* __restrict__ bias, const int* __restrict__ idxp,
    const int* __restrict__ counter,
    unsigned short* __restrict__ Hout, float* __restrict__ Cout)
{
  constexpr int MT = TOKENS / 128;           // 128 row tiles (max)
  constexpr int NWG = (N / 128) * MT;
  constexpr int q = NWG / 8, r = NWG % 8;
  int wg = blockIdx.x;
  int xcd = wg & 7, lin = wg >> 3;
  int swz = (xcd < r ? xcd * (q + 1) : r * (q + 1) + (xcd - r) * q) + lin;
  int colb = swz / MT;                       // col-major: same col contiguous
  int rowb = swz % MT;

  int cnt = *counter;
  int row0 = rowb * 128;
  if (row0 >= cnt) return;
  int col0 = colb * 128;

  __shared__ unsigned short As[128 * 32];
  __shared__ unsigned short Bs[128 * 32];
  __shared__ int rowIdx[128];

  int tid = threadIdx.x, wid = tid >> 6, lane = tid & 63;
  if (tid < 128) rowIdx[tid] = idxp[row0 + tid];
  __syncthreads();

  // staging addresses: each thread owns two 16B chunks per K-step
  int sRow0 = wid * 16 + (lane >> 2);
  int sRow1 = 64 + sRow0;
  int chunk = (lane & 3) * 8;
  int ar0 = FIRST ? rowIdx[sRow0] : (row0 + sRow0);
  int ar1 = FIRST ? rowIdx[sRow1] : (row0 + sRow1);
  const unsigned short* gA0 = A + (size_t)ar0 * K + chunk;
  const unsigned short* gA1 = A + (size_t)ar1 * K + chunk;
  const unsigned short* gB0 = Bt + (size_t)(col0 + sRow0) * K + chunk;
  const unsigned short* gB1 = Bt + (size_t)(col0 + sRow1) * K + chunk;
  unsigned short* lA0 = As + (size_t)(wid * 16) * 32;        // wave-uniform bases
  unsigned short* lA1 = As + (size_t)(64 + wid * 16) * 32;
  unsigned short* lB0 = Bs + (size_t)(wid * 16) * 32;
  unsigned short* lB1 = Bs + (size_t)(64 + wid * 16) * 32;

  f32x4 acc[4][4];
#pragma unroll
  for (int i = 0; i < 4; ++i)
#pragma unroll
    for (int j = 0; j < 4; ++j) acc[i][j] = (f32x4){0.f, 0.f, 0.f, 0.f};

  int wr = (wid >> 1) * 64, wc = (wid & 1) * 64;
  int frow = lane & 15, khalf = lane >> 4;

  for (int k0 = 0; k0 < K; k0 += 32) {
    async16(gA0 + k0, lA0);
    async16(gA1 + k0, lA1);
    async16(gB0 + k0, lB0);
    async16(gB1 + k0, lB1);
    __syncthreads();   // drains vmcnt(0) before barrier -> LDS tile visible
    short8 af[4], bfr[4];
#pragma unroll
    for (int mi = 0; mi < 4; ++mi)
      af[mi] = *(const short8*)&As[(size_t)(wr + mi * 16 + frow) * 32 + khalf * 8];
#pragma unroll
    for (int ni = 0; ni < 4; ++ni)
      bfr[ni] = *(const short8*)&Bs[(size_t)(wc + ni * 16 + frow) * 32 + khalf * 8];
#pragma unroll
    for (int mi = 0; mi < 4; ++mi)
#pragma unroll
      for (int ni = 0; ni < 4; ++ni)
        acc[mi][ni] = __builtin_amdgcn_mfma_f32_16x16x32_bf16(af[mi], bfr[ni], acc[mi][ni], 0, 0, 0);
    __syncthreads();   // protect LDS before next stage overwrites
  }

  // epilogue: C/D layout col = lane&15, row = (lane>>4)*4 + reg   [m89/m91]
  int cl = lane & 15, rq = lane >> 4;
#pragma unroll
  for (int mi = 0; mi < 4; ++mi) {
#pragma unroll
    for (int ni = 0; ni < 4; ++ni) {
      int col = col0 + wc + ni * 16 + cl;
      float bv = bias[col];
#pragma unroll
      for (int r2 = 0; r2 < 4; ++r2) {
        int rloc = wr + mi * 16 + rq * 4 + r2;
        int grow = row0 + rloc;
        float val = acc[mi][ni][r2] + bv;
        if (FIRST) {
          val = val > 0.f ? val : 0.f;
          Hout[(size_t)grow * N + col] = f2bf(val);
        } else if (grow < cnt) {
          int tok = rowIdx[rloc];
          Cout[(size_t)tok * DIM + col] = val;
        }
      }
    }
  }
}

// ---------------------------------------------------------------------------
extern "C" void kernel_launch(void* const* d_in, const int* in_sizes, int n_in,
                              void* d_out, int out_size, void* d_ws, size_t ws_size,
                              hipStream_t stream)
{
  const float* x  = (const float*)d_in[0];
  const float* Wr = (const float*)d_in[1];
  const float* br = (const float*)d_in[2];
  const float* W1 = (const float*)d_in[3];
  const float* b1 = (const float*)d_in[4];
  const float* W2 = (const float*)d_in[5];
  const float* b2 = (const float*)d_in[6];
  float* out = (float*)d_out;

  char* ws = (char*)d_ws;
  int* counter        = (int*)ws;                          // 4 B (zeroed)
  int* idx            = (int*)(ws + 256);                  // 64 KB (zeroed)
  unsigned short* xb  = (unsigned short*)(ws + (1ull  << 20));  // 32 MB bf16 x
  unsigned short* W1T = (unsigned short*)(ws + (34ull << 20));  // 8 MB  bf16 W1^T [4096][1024]
  unsigned short* W2T = (unsigned short*)(ws + (44ull << 20));  // 8 MB  bf16 W2^T [1024][4096]
  unsigned short* h   = (unsigned short*)(ws + (54ull << 20));  // 128 MB bf16 h (worst case)

  hipMemsetAsync(ws, 0, 256 + TOKENS * 4, stream);  // counter + idx

  router_kernel<<<TOKENS / 16, 256, 0, stream>>>(x, Wr, br, out, xb, idx, counter);
  transpose_cast_kernel<<<dim3(HID / 32, DIM / 32), 256, 0, stream>>>(W1, W1T, DIM, HID);
  transpose_cast_kernel<<<dim3(DIM / 32, HID / 32), 256, 0, stream>>>(W2, W2T, HID, DIM);
  frac_kernel<<<1, 1, 0, stream>>>(counter, out + (size_t)TOKENS * DIM);

  gemm_kernel<HID, DIM, true><<<(HID / 128) * (TOKENS / 128), 256, 0, stream>>>(
      xb, W1T, b1, idx, counter, h, nullptr);
  gemm_kernel<DIM, HID, false><<<(DIM / 128) * (TOKENS / 128), 256, 0, stream>>>(
      h, W2T, b2, idx, counter, nullptr, out);
}